// Round 1
// baseline (230.420 us; speedup 1.0000x reference)
//
#include <hip/hip_runtime.h>
#include <cstdint>

#define CKDIM 128
#define MDIM  4096
#define QDIM  4096
#define BATCH 4

typedef __attribute__((ext_vector_type(8))) short short8;
typedef __attribute__((ext_vector_type(4))) float f32x4;

#if __has_builtin(__builtin_amdgcn_exp2f)
#define EXP2(x) __builtin_amdgcn_exp2f(x)
#else
#define EXP2(x) exp2f(x)
#endif

__device__ inline unsigned short f2bf(float f) {
    unsigned u = __builtin_bit_cast(unsigned, f);
    unsigned r = (u + 0x7FFFu + ((u >> 16) & 1u)) >> 16;   // RNE
    return (unsigned short)r;
}
__device__ inline float bf2f(unsigned short h) {
    unsigned u = ((unsigned)h) << 16;
    return __builtin_bit_cast(float, u);
}

// ---- 1) squared norms of memory keys: asq[b][m] = sum_c mk[b][c][m]^2 (fp32 exact)
__global__ void asq_kernel(const float* __restrict__ Mk, float* __restrict__ asq) {
    int i = blockIdx.x * blockDim.x + threadIdx.x;      // < BATCH*MDIM
    int b = i >> 12;
    int m = i & (MDIM - 1);
    const float* p = Mk + (size_t)b * CKDIM * MDIM + m;
    float s = 0.f;
    #pragma unroll 8
    for (int c = 0; c < CKDIM; ++c) { float v = p[(size_t)c * MDIM]; s += v * v; }
    asq[i] = s;
}

// ---- 2) GEMM (bf16 hi/lo x3 MFMA) + exp + column-sum atomics
// Block tile 128(m) x 128(q), 4 waves in 2x2, K staged 64 at a time.
// LDS layout per matrix: [n=128][k=64] bf16, k-block XOR swizzle k' = k ^ ((n&7)<<3).
__launch_bounds__(256, 2)
__global__ void gemm_exp_kernel(const float* __restrict__ Mk, const float* __restrict__ Qk,
                                const float* __restrict__ asq, float* __restrict__ sums,
                                float* __restrict__ out) {
    __shared__ unsigned short smem[4 * 128 * 64];   // A_hi, A_lo, B_hi, B_lo : 64 KB
    const int tid  = threadIdx.x;
    const int lane = tid & 63;
    const int wid  = tid >> 6;
    const int wr   = wid >> 1;      // wave row 0..1 (64 m each)
    const int wc   = wid & 1;       // wave col 0..1 (64 q each)
    const int bq0  = blockIdx.x * 128;
    const int bm0  = blockIdx.y * 128;
    const int b    = blockIdx.z;

    const float* Ag = Mk + (size_t)b * CKDIM * MDIM;   // [c][m]
    const float* Bg = Qk + (size_t)b * CKDIM * QDIM;   // [c][q]

    f32x4 acc[4][4];
    #pragma unroll
    for (int i = 0; i < 4; ++i)
        #pragma unroll
        for (int j = 0; j < 4; ++j) acc[i][j] = (f32x4){0.f, 0.f, 0.f, 0.f};

    for (int kt = 0; kt < CKDIM; kt += 64) {
        __syncthreads();   // protect previous iteration's fragment reads
        // stage A (mat=0) and B (mat=1): 8 fp32 along k per thread -> hi/lo b128 writes
        #pragma unroll
        for (int mat = 0; mat < 2; ++mat) {
            const float* src = mat ? Bg : Ag;
            const int    n0  = mat ? bq0 : bm0;
            unsigned short* hi_base = smem + (mat * 2 + 0) * 8192;
            unsigned short* lo_base = smem + (mat * 2 + 1) * 8192;
            #pragma unroll
            for (int it = 0; it < 4; ++it) {
                int pid = it * 256 + tid;
                int n   = pid & 127;
                int c8  = pid >> 7;            // 0..7 (k-block of 8)
                const float* g = src + (size_t)(kt + c8 * 8) * MDIM + (n0 + n);
                float v[8];
                #pragma unroll
                for (int j = 0; j < 8; ++j) v[j] = g[(size_t)j * MDIM];
                unsigned short h[8], l[8];
                #pragma unroll
                for (int j = 0; j < 8; ++j) {
                    h[j] = f2bf(v[j]);
                    l[j] = f2bf(v[j] - bf2f(h[j]));
                }
                int off = n * 64 + ((c8 * 8) ^ ((n & 7) << 3));
                uint4 whi = make_uint4((unsigned)h[0] | ((unsigned)h[1] << 16),
                                       (unsigned)h[2] | ((unsigned)h[3] << 16),
                                       (unsigned)h[4] | ((unsigned)h[5] << 16),
                                       (unsigned)h[6] | ((unsigned)h[7] << 16));
                uint4 wlo = make_uint4((unsigned)l[0] | ((unsigned)l[1] << 16),
                                       (unsigned)l[2] | ((unsigned)l[3] << 16),
                                       (unsigned)l[4] | ((unsigned)l[5] << 16),
                                       (unsigned)l[6] | ((unsigned)l[7] << 16));
                *(uint4*)&hi_base[off] = whi;
                *(uint4*)&lo_base[off] = wlo;
            }
        }
        __syncthreads();
        // two k-steps of 32
        #pragma unroll
        for (int t = 0; t < 2; ++t) {
            const int g  = lane >> 4;
            const int i  = lane & 15;
            const int kl = t * 32 + g * 8;
            short8 ah[4], al[4], bh[4], bl[4];
            #pragma unroll
            for (int mf = 0; mf < 4; ++mf) {
                int n   = wr * 64 + mf * 16 + i;
                int off = n * 64 + (kl ^ ((n & 7) << 3));
                ah[mf] = *(const short8*)&smem[0 * 8192 + off];
                al[mf] = *(const short8*)&smem[1 * 8192 + off];
            }
            #pragma unroll
            for (int nf = 0; nf < 4; ++nf) {
                int n   = wc * 64 + nf * 16 + i;
                int off = n * 64 + (kl ^ ((n & 7) << 3));
                bh[nf] = *(const short8*)&smem[2 * 8192 + off];
                bl[nf] = *(const short8*)&smem[3 * 8192 + off];
            }
            #pragma unroll
            for (int mf = 0; mf < 4; ++mf)
                #pragma unroll
                for (int nf = 0; nf < 4; ++nf) {
                    acc[mf][nf] = __builtin_amdgcn_mfma_f32_16x16x32_bf16(ah[mf], bh[nf], acc[mf][nf], 0, 0, 0);
                    acc[mf][nf] = __builtin_amdgcn_mfma_f32_16x16x32_bf16(ah[mf], bl[nf], acc[mf][nf], 0, 0, 0);
                    acc[mf][nf] = __builtin_amdgcn_mfma_f32_16x16x32_bf16(al[mf], bh[nf], acc[mf][nf], 0, 0, 0);
                }
        }
    }

    // ---- epilogue: E = exp2(alpha*(2ab - asq)), store E, column partial sums
    const float ALPHA = 1.44269504088896340736f / 11.31370849898476039041f; // log2(e)/sqrt(128)
    const int g = lane >> 4;
    const int i = lane & 15;
    float colsum[4] = {0.f, 0.f, 0.f, 0.f};
    #pragma unroll
    for (int mf = 0; mf < 4; ++mf) {
        int   mbase = bm0 + wr * 64 + mf * 16 + g * 4;
        f32x4 aq    = *(const f32x4*)&asq[b * MDIM + mbase];
        #pragma unroll
        for (int nf = 0; nf < 4; ++nf) {
            int    q       = bq0 + wc * 64 + nf * 16 + i;
            size_t outbase = ((size_t)b * MDIM + mbase) * QDIM + q;
            #pragma unroll
            for (int r = 0; r < 4; ++r) {
                float t2 = 2.0f * acc[mf][nf][r] - aq[r];
                float e  = EXP2(t2 * ALPHA);
                colsum[nf] += e;
                out[outbase + (size_t)r * QDIM] = e;
            }
        }
    }
    #pragma unroll
    for (int nf = 0; nf < 4; ++nf) {
        float s = colsum[nf];
        s += __shfl_xor(s, 16);
        s += __shfl_xor(s, 32);
        if (lane < 16) {
            __hip_atomic_fetch_add(&sums[(b << 12) + bq0 + wc * 64 + nf * 16 + lane], s,
                                   __ATOMIC_RELAXED, __HIP_MEMORY_SCOPE_AGENT);
        }
    }
}

// ---- 3) reciprocal of column sums
__global__ void rsum_kernel(const float* __restrict__ sums, float* __restrict__ rsum) {
    int i = blockIdx.x * blockDim.x + threadIdx.x;
    if (i < BATCH * QDIM) rsum[i] = 1.0f / sums[i];
}

// ---- 4) normalize: out[b][m][q] *= rsum[b][q]  (float4 streaming)
__global__ void norm_kernel(float* __restrict__ out, const float* __restrict__ rsum) {
    const size_t total4 = (size_t)BATCH * MDIM * QDIM / 4;
    size_t idx    = (size_t)blockIdx.x * blockDim.x + threadIdx.x;
    size_t stride = (size_t)gridDim.x * blockDim.x;
    for (; idx < total4; idx += stride) {
        size_t f = idx * 4;
        int q = (int)(f & (QDIM - 1));
        int b = (int)(f >> 24);                 // M*Q = 2^24
        f32x4 rs = *(const f32x4*)&rsum[(b << 12) + q];
        f32x4 o  = *(f32x4*)&out[f];
        o *= rs;
        *(f32x4*)&out[f] = o;
    }
}

extern "C" void kernel_launch(void* const* d_in, const int* in_sizes, int n_in,
                              void* d_out, int out_size, void* d_ws, size_t ws_size,
                              hipStream_t stream) {
    const float* Mk = (const float*)d_in[0];
    const float* Qk = (const float*)d_in[1];
    float* out  = (float*)d_out;
    float* sums = (float*)d_ws;                   // [BATCH*QDIM]
    float* asq  = sums + BATCH * QDIM;            // [BATCH*MDIM]
    float* rsum = asq + BATCH * MDIM;             // [BATCH*QDIM]

    hipMemsetAsync(sums, 0, BATCH * QDIM * sizeof(float), stream);
    asq_kernel<<<BATCH * MDIM / 256, 256, 0, stream>>>(Mk, asq);
    dim3 grid(QDIM / 128, MDIM / 128, BATCH);
    gemm_exp_kernel<<<grid, 256, 0, stream>>>(Mk, Qk, asq, sums, out);
    rsum_kernel<<<BATCH * QDIM / 256, 256, 0, stream>>>(sums, rsum);
    norm_kernel<<<2048, 256, 0, stream>>>(out, rsum);
}

// Round 2
// 107.251 us; speedup vs baseline: 2.1484x; 2.1484x over previous
//
#include <hip/hip_runtime.h>
#include <cstdint>

#define CKDIM 128
#define MDIM  4096
#define QDIM  4096
#define BATCH 4

typedef __attribute__((ext_vector_type(8))) _Float16 half8;
typedef __attribute__((ext_vector_type(4))) float    f32x4;

#if __has_builtin(__builtin_amdgcn_exp2f)
#define EXP2(x) __builtin_amdgcn_exp2f(x)
#else
#define EXP2(x) exp2f(x)
#endif

__device__ inline void gl_lds16(const void* g, const void* l) {
    __builtin_amdgcn_global_load_lds(
        (const __attribute__((address_space(1))) unsigned*)g,
        (__attribute__((address_space(3))) unsigned*)l, 16, 0, 0);
}

// ---- 1) transpose-convert: X[b][k][n] fp32 -> Xt[b][n][k] fp16 (plain layout;
//         GEMM applies the LDS swizzle via per-lane source addresses)
__global__ void convert_kernel(const float* __restrict__ Mk, const float* __restrict__ Qk,
                               _Float16* __restrict__ At, _Float16* __restrict__ Bt) {
    __shared__ _Float16 T[128 * 130];            // [k][n], pad 2 to break bank alias
    const int blk = blockIdx.x;                  // 256 blocks: mat(2) x b(4) x tile(32)
    const int mat = blk >> 7;
    const int b   = (blk >> 5) & 3;
    const int t   = blk & 31;
    const float*  src = (mat ? Qk : Mk) + (size_t)b * CKDIM * MDIM + t * 128;
    _Float16*     dst = (mat ? Bt : At) + ((size_t)b * MDIM + (size_t)t * 128) * CKDIM;
    const int tid = threadIdx.x;
    #pragma unroll
    for (int it = 0; it < 8; ++it) {             // coalesced read along n
        int pid = it * 256 + tid;
        int k = pid >> 4, ng = pid & 15;
        const float* g = src + (size_t)k * MDIM + ng * 8;
        float4 v0 = *(const float4*)g;
        float4 v1 = *(const float4*)(g + 4);
        _Float16* p = &T[k * 130 + ng * 8];
        p[0] = (_Float16)v0.x; p[1] = (_Float16)v0.y; p[2] = (_Float16)v0.z; p[3] = (_Float16)v0.w;
        p[4] = (_Float16)v1.x; p[5] = (_Float16)v1.y; p[6] = (_Float16)v1.z; p[7] = (_Float16)v1.w;
    }
    __syncthreads();
    #pragma unroll
    for (int it = 0; it < 8; ++it) {             // gather column, coalesced 16B store
        int pid = it * 256 + tid;
        int n = pid >> 4, c = pid & 15;
        half8 o;
        #pragma unroll
        for (int j = 0; j < 8; ++j) o[j] = T[(c * 8 + j) * 130 + n];
        *(half8*)(dst + (size_t)n * CKDIM + c * 8) = o;
    }
}

// ---- 2) squared norms (fp32 exact): asq[b][m] = sum_c Mk[b][c][m]^2
__global__ void asq_kernel(const float* __restrict__ Mk, float* __restrict__ asq) {
    int i = blockIdx.x * blockDim.x + threadIdx.x;
    int b = i >> 12;
    int m = i & (MDIM - 1);
    const float* p = Mk + (size_t)b * CKDIM * MDIM + m;
    float s = 0.f;
    #pragma unroll 8
    for (int c = 0; c < CKDIM; ++c) { float v = p[(size_t)c * MDIM]; s += v * v; }
    asq[i] = s;
}

// ---- 3/5) GEMM passes. 128x128 tile, 2x2 waves, full K=128 in LDS (one stage).
// WRITE=0: exp + column-sum atomics (no output write). WRITE=1: write exp*rsum.
template <int WRITE>
__global__ __launch_bounds__(256, 2) void gemm_pass(
        const _Float16* __restrict__ At, const _Float16* __restrict__ Bt,
        const float* __restrict__ asq, float* __restrict__ sums,
        const float* __restrict__ rsum, float* __restrict__ out) {
    __shared__ unsigned short smem[2 * 128 * 128];   // A(32KB) | B(32KB)
    const int tid  = threadIdx.x;
    const int lane = tid & 63;
    const int wv   = tid >> 6;
    const int wr   = wv >> 1;
    const int wc   = wv & 1;
    const int bq0  = blockIdx.x * 128;
    const int bm0  = blockIdx.y * 128;
    const int b    = blockIdx.z;

    // stage: linear LDS dest, inverse-swizzled per-lane global source
    const char* Abase = (const char*)(At + ((size_t)b * MDIM + bm0) * CKDIM);
    const char* Bbase = (const char*)(Bt + ((size_t)b * QDIM + bq0) * CKDIM);
    char* lA = (char*)smem;
    char* lB = (char*)smem + 32768;
    #pragma unroll
    for (int r = 0; r < 8; ++r) {
        unsigned Dw = (unsigned)(r * 4 + wv) * 1024;       // wave-uniform dest base
        unsigned D  = Dw + (unsigned)lane * 16;
        unsigned S  = D ^ (((D >> 8) & 7u) << 4);          // st_16x32-style swizzle
        gl_lds16(Abase + S, lA + Dw);
        gl_lds16(Bbase + S, lB + Dw);
    }
    asm volatile("s_waitcnt vmcnt(0)" ::: "memory");
    __syncthreads();

    const int g4 = lane >> 4;      // k-group
    const int i  = lane & 15;      // fragment row/col
    f32x4 acc[4][4];
    #pragma unroll
    for (int mf = 0; mf < 4; ++mf)
        #pragma unroll
        for (int nf = 0; nf < 4; ++nf) acc[mf][nf] = (f32x4){0.f, 0.f, 0.f, 0.f};

    #pragma unroll
    for (int t = 0; t < 4; ++t) {                  // K = 4 x 32
        const int kb = t * 64 + g4 * 16;           // byte offset within 256B row
        half8 af[4], bfr[4];
        #pragma unroll
        for (int mf = 0; mf < 4; ++mf) {
            int n = wr * 64 + mf * 16 + i;
            af[mf] = *(const half8*)(lA + n * 256 + (kb ^ ((n & 7) << 4)));
        }
        #pragma unroll
        for (int nf = 0; nf < 4; ++nf) {
            int n = wc * 64 + nf * 16 + i;
            bfr[nf] = *(const half8*)(lB + n * 256 + (kb ^ ((n & 7) << 4)));
        }
        #pragma unroll
        for (int mf = 0; mf < 4; ++mf)
            #pragma unroll
            for (int nf = 0; nf < 4; ++nf)
                acc[mf][nf] = __builtin_amdgcn_mfma_f32_16x16x32_f16(af[mf], bfr[nf], acc[mf][nf], 0, 0, 0);
    }

    const float ALPHA = 1.44269504088896340736f / 11.31370849898476039041f; // log2(e)/sqrt(128)
    if (WRITE) {
        float rs[4];
        #pragma unroll
        for (int nf = 0; nf < 4; ++nf) rs[nf] = rsum[(b << 12) + bq0 + wc * 64 + nf * 16 + i];
        #pragma unroll
        for (int mf = 0; mf < 4; ++mf) {
            int   mbase = bm0 + wr * 64 + mf * 16 + g4 * 4;
            f32x4 aq    = *(const f32x4*)&asq[b * MDIM + mbase];
            #pragma unroll
            for (int nf = 0; nf < 4; ++nf) {
                size_t outbase = ((size_t)b * MDIM + mbase) * QDIM + (bq0 + wc * 64 + nf * 16 + i);
                #pragma unroll
                for (int r = 0; r < 4; ++r) {
                    float e = EXP2((2.0f * acc[mf][nf][r] - aq[r]) * ALPHA);
                    out[outbase + (size_t)r * QDIM] = e * rs[nf];
                }
            }
        }
    } else {
        float colsum[4] = {0.f, 0.f, 0.f, 0.f};
        #pragma unroll
        for (int mf = 0; mf < 4; ++mf) {
            int   mbase = bm0 + wr * 64 + mf * 16 + g4 * 4;
            f32x4 aq    = *(const f32x4*)&asq[b * MDIM + mbase];
            #pragma unroll
            for (int nf = 0; nf < 4; ++nf)
                #pragma unroll
                for (int r = 0; r < 4; ++r)
                    colsum[nf] += EXP2((2.0f * acc[mf][nf][r] - aq[r]) * ALPHA);
        }
        #pragma unroll
        for (int nf = 0; nf < 4; ++nf) {
            float s = colsum[nf];
            s += __shfl_xor(s, 16);
            s += __shfl_xor(s, 32);
            if (lane < 16) {
                __hip_atomic_fetch_add(&sums[(b << 12) + bq0 + wc * 64 + nf * 16 + lane], s,
                                       __ATOMIC_RELAXED, __HIP_MEMORY_SCOPE_AGENT);
            }
        }
    }
}

// ---- 4) reciprocal of column sums
__global__ void rsum_kernel(const float* __restrict__ sums, float* __restrict__ rsum) {
    int i = blockIdx.x * blockDim.x + threadIdx.x;
    if (i < BATCH * QDIM) rsum[i] = 1.0f / sums[i];
}

extern "C" void kernel_launch(void* const* d_in, const int* in_sizes, int n_in,
                              void* d_out, int out_size, void* d_ws, size_t ws_size,
                              hipStream_t stream) {
    const float* Mk = (const float*)d_in[0];
    const float* Qk = (const float*)d_in[1];
    float* out = (float*)d_out;

    _Float16* At  = (_Float16*)d_ws;                               // 4 MB
    _Float16* Bt  = At + (size_t)BATCH * MDIM * CKDIM;             // 4 MB
    float*    sums = (float*)(Bt + (size_t)BATCH * MDIM * CKDIM);  // 64 KB
    float*    asq  = sums + BATCH * QDIM;                          // 64 KB
    float*    rsum = asq + BATCH * MDIM;                           // 64 KB

    convert_kernel<<<256, 256, 0, stream>>>(Mk, Qk, At, Bt);
    asq_kernel<<<BATCH * MDIM / 256, 256, 0, stream>>>(Mk, asq);
    hipMemsetAsync(sums, 0, BATCH * QDIM * sizeof(float), stream);
    dim3 grid(QDIM / 128, MDIM / 128, BATCH);
    gemm_pass<0><<<grid, 256, 0, stream>>>(At, Bt, asq, sums, rsum, out);
    rsum_kernel<<<BATCH * QDIM / 256, 256, 0, stream>>>(sums, rsum);
    gemm_pass<1><<<grid, 256, 0, stream>>>(At, Bt, asq, sums, rsum, out);
}

// Round 3
// 107.195 us; speedup vs baseline: 2.1495x; 1.0005x over previous
//
#include <hip/hip_runtime.h>
#include <cstdint>

#define CKDIM 128
#define MDIM  4096
#define QDIM  4096
#define BATCH 4

typedef __attribute__((ext_vector_type(8))) _Float16 half8;
typedef __attribute__((ext_vector_type(4))) float    f32x4;

#if __has_builtin(__builtin_amdgcn_exp2f)
#define EXP2(x) __builtin_amdgcn_exp2f(x)
#else
#define EXP2(x) exp2f(x)
#endif

__device__ inline void gl_lds16(const void* g, const void* l) {
    __builtin_amdgcn_global_load_lds(
        (const __attribute__((address_space(1))) unsigned*)g,
        (__attribute__((address_space(3))) unsigned*)l, 16, 0, 0);
}

// ---- 1) fused: transpose-convert X[b][k][n] fp32 -> Xt[b][n][k] fp16,
//      asq[b][m] = sum_k Mk^2 (fp32-exact, accumulated pre-rounding),
//      and zeroing of sums[] (done by the Qk half of the grid).
__global__ void convert_kernel(const float* __restrict__ Mk, const float* __restrict__ Qk,
                               _Float16* __restrict__ At, _Float16* __restrict__ Bt,
                               float* __restrict__ asq, float* __restrict__ sums) {
    __shared__ _Float16 T[128 * 130];            // [k][n], +2 pad
    __shared__ float    asqp[16][128];           // k-group partials (Mk blocks only)
    const int blk = blockIdx.x;                  // 256 blocks: mat(2) x b(4) x tile(32)
    const int mat = blk >> 7;
    const int b   = (blk >> 5) & 3;
    const int t   = blk & 31;
    const float*  src = (mat ? Qk : Mk) + (size_t)b * CKDIM * MDIM + t * 128;
    _Float16*     dst = (mat ? Bt : At) + ((size_t)b * MDIM + (size_t)t * 128) * CKDIM;
    const int tid = threadIdx.x;
    const int kg  = tid >> 4;                    // 0..15 (fixed across iterations)
    const int ng  = tid & 15;                    // 0..15 (fixed across iterations)

    float sq[8] = {0.f, 0.f, 0.f, 0.f, 0.f, 0.f, 0.f, 0.f};
    #pragma unroll
    for (int it = 0; it < 8; ++it) {             // coalesced read along n
        int k = it * 16 + kg;
        const float* g = src + (size_t)k * MDIM + ng * 8;
        float4 v0 = *(const float4*)g;
        float4 v1 = *(const float4*)(g + 4);
        _Float16* p = &T[k * 130 + ng * 8];
        p[0] = (_Float16)v0.x; p[1] = (_Float16)v0.y; p[2] = (_Float16)v0.z; p[3] = (_Float16)v0.w;
        p[4] = (_Float16)v1.x; p[5] = (_Float16)v1.y; p[6] = (_Float16)v1.z; p[7] = (_Float16)v1.w;
        if (mat == 0) {
            sq[0] += v0.x * v0.x; sq[1] += v0.y * v0.y;
            sq[2] += v0.z * v0.z; sq[3] += v0.w * v0.w;
            sq[4] += v1.x * v1.x; sq[5] += v1.y * v1.y;
            sq[6] += v1.z * v1.z; sq[7] += v1.w * v1.w;
        }
    }
    if (mat == 0) {
        #pragma unroll
        for (int j = 0; j < 8; ++j) asqp[kg][ng * 8 + j] = sq[j];
    } else {
        // Qk half of grid zeroes sums[]: 128 blocks x 128 floats = 16384
        if (tid < 128) sums[(blk & 127) * 128 + tid] = 0.f;
    }
    __syncthreads();
    #pragma unroll
    for (int it = 0; it < 8; ++it) {             // gather column, coalesced 16B store
        int pid = it * 256 + tid;
        int n = pid >> 4, c = pid & 15;
        half8 o;
        #pragma unroll
        for (int j = 0; j < 8; ++j) o[j] = T[(c * 8 + j) * 130 + n];
        *(half8*)(dst + (size_t)n * CKDIM + c * 8) = o;
    }
    if (mat == 0 && tid < 128) {
        float s = 0.f;
        #pragma unroll
        for (int g = 0; g < 16; ++g) s += asqp[g][tid];
        asq[b * MDIM + t * 128 + tid] = s;
    }
}

// ---- 2/3) GEMM passes. 128x128 tile, 2x2 waves, full K=128 in LDS (one stage).
// WRITE=0: exp + column-sum atomics (no output write). WRITE=1: write exp/sum.
template <int WRITE>
__global__ __launch_bounds__(256, 2) void gemm_pass(
        const _Float16* __restrict__ At, const _Float16* __restrict__ Bt,
        const float* __restrict__ asq, float* __restrict__ sums,
        float* __restrict__ out) {
    __shared__ unsigned short smem[2 * 128 * 128];   // A(32KB) | B(32KB)
    const int tid  = threadIdx.x;
    const int lane = tid & 63;
    const int wv   = tid >> 6;
    const int wr   = wv >> 1;
    const int wc   = wv & 1;
    const int bq0  = blockIdx.x * 128;
    const int bm0  = blockIdx.y * 128;
    const int b    = blockIdx.z;

    // stage: linear LDS dest, inverse-swizzled per-lane global source
    const char* Abase = (const char*)(At + ((size_t)b * MDIM + bm0) * CKDIM);
    const char* Bbase = (const char*)(Bt + ((size_t)b * QDIM + bq0) * CKDIM);
    char* lA = (char*)smem;
    char* lB = (char*)smem + 32768;
    #pragma unroll
    for (int r = 0; r < 8; ++r) {
        unsigned Dw = (unsigned)(r * 4 + wv) * 1024;       // wave-uniform dest base
        unsigned D  = Dw + (unsigned)lane * 16;
        unsigned S  = D ^ (((D >> 8) & 7u) << 4);          // st_16x32-style swizzle
        gl_lds16(Abase + S, lA + Dw);
        gl_lds16(Bbase + S, lB + Dw);
    }
    asm volatile("s_waitcnt vmcnt(0)" ::: "memory");
    __syncthreads();

    const int g4 = lane >> 4;      // k-group
    const int i  = lane & 15;      // fragment row/col
    f32x4 acc[4][4];
    #pragma unroll
    for (int mf = 0; mf < 4; ++mf)
        #pragma unroll
        for (int nf = 0; nf < 4; ++nf) acc[mf][nf] = (f32x4){0.f, 0.f, 0.f, 0.f};

    #pragma unroll
    for (int t = 0; t < 4; ++t) {                  // K = 4 x 32
        const int kb = t * 64 + g4 * 16;           // byte offset within 256B row
        half8 af[4], bfr[4];
        #pragma unroll
        for (int mf = 0; mf < 4; ++mf) {
            int n = wr * 64 + mf * 16 + i;
            af[mf] = *(const half8*)(lA + n * 256 + (kb ^ ((n & 7) << 4)));
        }
        #pragma unroll
        for (int nf = 0; nf < 4; ++nf) {
            int n = wc * 64 + nf * 16 + i;
            bfr[nf] = *(const half8*)(lB + n * 256 + (kb ^ ((n & 7) << 4)));
        }
        #pragma unroll
        for (int mf = 0; mf < 4; ++mf)
            #pragma unroll
            for (int nf = 0; nf < 4; ++nf)
                acc[mf][nf] = __builtin_amdgcn_mfma_f32_16x16x32_f16(af[mf], bfr[nf], acc[mf][nf], 0, 0, 0);
    }

    const float ALPHA = 1.44269504088896340736f / 11.31370849898476039041f; // log2(e)/sqrt(128)
    if (WRITE) {
        float rs[4];
        #pragma unroll
        for (int nf = 0; nf < 4; ++nf)
            rs[nf] = 1.0f / sums[(b << 12) + bq0 + wc * 64 + nf * 16 + i];
        #pragma unroll
        for (int mf = 0; mf < 4; ++mf) {
            int   mbase = bm0 + wr * 64 + mf * 16 + g4 * 4;
            f32x4 aq    = *(const f32x4*)&asq[b * MDIM + mbase];
            #pragma unroll
            for (int nf = 0; nf < 4; ++nf) {
                size_t outbase = ((size_t)b * MDIM + mbase) * QDIM + (bq0 + wc * 64 + nf * 16 + i);
                #pragma unroll
                for (int r = 0; r < 4; ++r) {
                    float e = EXP2((2.0f * acc[mf][nf][r] - aq[r]) * ALPHA);
                    __builtin_nontemporal_store(e * rs[nf], &out[outbase + (size_t)r * QDIM]);
                }
            }
        }
    } else {
        float colsum[4] = {0.f, 0.f, 0.f, 0.f};
        #pragma unroll
        for (int mf = 0; mf < 4; ++mf) {
            int   mbase = bm0 + wr * 64 + mf * 16 + g4 * 4;
            f32x4 aq    = *(const f32x4*)&asq[b * MDIM + mbase];
            #pragma unroll
            for (int nf = 0; nf < 4; ++nf)
                #pragma unroll
                for (int r = 0; r < 4; ++r)
                    colsum[nf] += EXP2((2.0f * acc[mf][nf][r] - aq[r]) * ALPHA);
        }
        #pragma unroll
        for (int nf = 0; nf < 4; ++nf) {
            float s = colsum[nf];
            s += __shfl_xor(s, 16);
            s += __shfl_xor(s, 32);
            if (lane < 16) {
                __hip_atomic_fetch_add(&sums[(b << 12) + bq0 + wc * 64 + nf * 16 + lane], s,
                                       __ATOMIC_RELAXED, __HIP_MEMORY_SCOPE_AGENT);
            }
        }
    }
}

extern "C" void kernel_launch(void* const* d_in, const int* in_sizes, int n_in,
                              void* d_out, int out_size, void* d_ws, size_t ws_size,
                              hipStream_t stream) {
    const float* Mk = (const float*)d_in[0];
    const float* Qk = (const float*)d_in[1];
    float* out = (float*)d_out;

    _Float16* At   = (_Float16*)d_ws;                               // 4 MB
    _Float16* Bt   = At + (size_t)BATCH * MDIM * CKDIM;             // 4 MB
    float*    sums = (float*)(Bt + (size_t)BATCH * MDIM * CKDIM);   // 64 KB
    float*    asq  = sums + BATCH * QDIM;                           // 64 KB

    convert_kernel<<<256, 256, 0, stream>>>(Mk, Qk, At, Bt, asq, sums);
    dim3 grid(QDIM / 128, MDIM / 128, BATCH);
    gemm_pass<0><<<grid, 256, 0, stream>>>(At, Bt, asq, sums, out);
    gemm_pass<1><<<grid, 256, 0, stream>>>(At, Bt, asq, sums, out);
}